// Round 4
// baseline (226.346 us; speedup 1.0000x reference)
//
#include <hip/hip_runtime.h>
#include <math.h>

#define EDIM 128
#define NHEAD 16
#define HDIM 8
#define SEQ 2048
#define BATCH 4
#define NROW (BATCH*SEQ)            // 8192
// -scale*log2(e): folded into Q at projection time so sigmoid = rcp(1+exp2(dot))
#define QNEG (-0.35355339059327373f * 1.4426950408889634f)

#if __has_builtin(__builtin_amdgcn_exp2f)
#define EXP2F(x) __builtin_amdgcn_exp2f(x)
#else
#define EXP2F(x) exp2f(x)
#endif
#define RCPF(x) __builtin_amdgcn_rcpf(x)

__device__ __forceinline__ float bflo(unsigned u) {
  return __uint_as_float(u << 16);
}
__device__ __forceinline__ float bfhi(unsigned u) {
  return __uint_as_float(u & 0xffff0000u);
}
// pack two floats to bf16x2, round-to-nearest-even (values are finite)
__device__ __forceinline__ unsigned pk_bf16(float a, float b) {
  unsigned ua = __float_as_uint(a), ub = __float_as_uint(b);
  unsigned lo = (ua + 0x7fffu + ((ua >> 16) & 1u)) >> 16;
  unsigned hi = (ub + 0x7fffu + ((ub >> 16) & 1u)) & 0xffff0000u;
  return lo | hi;
}

// ---------------------------------------------------------------------------
// Transpose the 4 weight matrices W[j][i] -> WT[i][j].
// ---------------------------------------------------------------------------
__global__ __launch_bounds__(256)
void transpose4_kernel(const float* __restrict__ W0, const float* __restrict__ W1,
                       const float* __restrict__ W2, const float* __restrict__ W3,
                       float* __restrict__ WT)
{
  const float* W = (blockIdx.y == 0) ? W0 : (blockIdx.y == 1) ? W1
                 : (blockIdx.y == 2) ? W2 : W3;
  float* out = WT + blockIdx.y * EDIM * EDIM;
  const int i0 = blockIdx.x * 16;
  #pragma unroll
  for (int it = 0; it < 8; ++it) {
    int f = threadIdx.x + it * 256;
    int i = i0 + (f >> 7);
    int j = f & 127;
    out[i * EDIM + j] = W[j * EDIM + i];
  }
}

// ---------------------------------------------------------------------------
// out = X @ W^T + b with pre-transposed WT. 32 rows x 128 cols per block
// (256 threads, thread = 4 rows x 4 cols) for full-GPU spread.
// mode 0: Q (scaled by QNEG) -> bf16 Qb[bh][s][8]  (4 dwords/row)
// mode 1: K -> bf16 in KVb[bh][s] dwords 0..3
// mode 2: V -> fp32 in KVb[bh][s] dwords 4..11
// mode 3: fp32 row-major [rows][128] (final output)
// ---------------------------------------------------------------------------
__device__ __forceinline__
void proj_body(const float* __restrict__ X, const float* __restrict__ WT,
               const float* __restrict__ bias, void* __restrict__ out, int mode)
{
  __shared__ float xs[32][EDIM];                  // 16 KB
  const int tid = threadIdx.x;
  const int row0 = blockIdx.x * 32;

  const float4* src = (const float4*)(X + row0 * EDIM);
  float4* dst = (float4*)(&xs[0][0]);
  #pragma unroll
  for (int t = 0; t < 4; ++t) dst[tid + t * 256] = src[tid + t * 256];
  __syncthreads();

  const int tc = tid & 31;
  const int tr = tid >> 5;                        // 0..7 (4 rows each)
  const int col0 = tc * 4;

  float acc[4][4];
  #pragma unroll
  for (int r = 0; r < 4; ++r)
    #pragma unroll
    for (int c = 0; c < 4; ++c) acc[r][c] = 0.f;

  #pragma unroll 2
  for (int ib = 0; ib < EDIM / 4; ++ib) {
    const float4 w0 = *(const float4*)(WT + (4 * ib + 0) * EDIM + col0);
    const float4 w1 = *(const float4*)(WT + (4 * ib + 1) * EDIM + col0);
    const float4 w2 = *(const float4*)(WT + (4 * ib + 2) * EDIM + col0);
    const float4 w3 = *(const float4*)(WT + (4 * ib + 3) * EDIM + col0);
    #pragma unroll
    for (int r = 0; r < 4; ++r) {
      const float4 x4 = *(const float4*)(&xs[tr * 4 + r][ib * 4]);  // b128 broadcast
      acc[r][0] += x4.x * w0.x + x4.y * w1.x + x4.z * w2.x + x4.w * w3.x;
      acc[r][1] += x4.x * w0.y + x4.y * w1.y + x4.z * w2.y + x4.w * w3.y;
      acc[r][2] += x4.x * w0.z + x4.y * w1.z + x4.z * w2.z + x4.w * w3.z;
      acc[r][3] += x4.x * w0.w + x4.y * w1.w + x4.z * w2.w + x4.w * w3.w;
    }
  }

  const float4 b4 = *(const float4*)(bias + col0);
  #pragma unroll
  for (int r = 0; r < 4; ++r) {
    const int grow = row0 + tr * 4 + r;
    const float4 o = make_float4(acc[r][0] + b4.x, acc[r][1] + b4.y,
                                 acc[r][2] + b4.z, acc[r][3] + b4.w);
    if (mode == 3) {
      *(float4*)((float*)out + (size_t)grow * EDIM + col0) = o;
    } else {
      const int b = grow >> 11, s = grow & (SEQ - 1);
      const int h = col0 >> 3, d0 = col0 & 7;     // d0 in {0,4}
      const size_t bhs = (size_t)(b * NHEAD + h) * SEQ + s;
      if (mode == 0) {
        uint2 p;
        p.x = pk_bf16(o.x * QNEG, o.y * QNEG);
        p.y = pk_bf16(o.z * QNEG, o.w * QNEG);
        *(uint2*)((unsigned*)out + bhs * 4 + (d0 >> 1)) = p;
      } else if (mode == 1) {
        uint2 p;
        p.x = pk_bf16(o.x, o.y);
        p.y = pk_bf16(o.z, o.w);
        *(uint2*)((unsigned*)out + bhs * 12 + (d0 >> 1)) = p;
      } else {
        *(float4*)((float*)out + bhs * 12 + 4 + d0) = o;
      }
    }
  }
}

__global__ __launch_bounds__(256)
void qkv_kernel(const float* __restrict__ X, const float* __restrict__ WT,
                const float* __restrict__ bq, const float* __restrict__ bk,
                const float* __restrict__ bv,
                unsigned* __restrict__ qb, unsigned* __restrict__ kvb)
{
  const int m = blockIdx.y;
  const float* wt   = WT + m * EDIM * EDIM;
  const float* bias = (m == 0) ? bq : (m == 1) ? bk : bv;
  void* out         = (m == 0) ? (void*)qb : (void*)kvb;
  proj_body(X, wt, bias, out, m);
}

__global__ __launch_bounds__(256)
void oproj_kernel(const float* __restrict__ A, const float* __restrict__ WTo,
                  const float* __restrict__ bo, float* __restrict__ out)
{
  proj_body(A, WTo, bo, (void*)out, 3);
}

// ---------------------------------------------------------------------------
// Attention inner tile: 64 keys from LDS (bf16 K + fp32 V, 48 B/key),
// 2 rows/lane. MASKED only for the two diagonal tiles (t >= 2m).
// ---------------------------------------------------------------------------
template<bool MASKED>
__device__ __forceinline__
void attn_tile(const unsigned* __restrict__ cur, int k0, int rowA, int rowB,
               const float* __restrict__ qA, const float* __restrict__ qB,
               float& denA, float& denB,
               float* __restrict__ accA, float* __restrict__ accB)
{
  #pragma unroll 4
  for (int j = 0; j < 64; ++j) {
    const unsigned* kvj = cur + j * 12;
    const uint4  kk = *(const uint4*)(kvj);       // K: bf16x8, broadcast b128
    const float4 va = *(const float4*)(kvj + 4);  // V: fp32, broadcast b128
    const float4 vb = *(const float4*)(kvj + 8);
    const float k0f = bflo(kk.x), k1f = bfhi(kk.x);
    const float k2f = bflo(kk.y), k3f = bfhi(kk.y);
    const float k4f = bflo(kk.z), k5f = bfhi(kk.z);
    const float k6f = bflo(kk.w), k7f = bfhi(kk.w);
    float dA = qA[0]*k0f + qA[1]*k1f + qA[2]*k2f + qA[3]*k3f
             + qA[4]*k4f + qA[5]*k5f + qA[6]*k6f + qA[7]*k7f;
    float dB = qB[0]*k0f + qB[1]*k1f + qB[2]*k2f + qB[3]*k3f
             + qB[4]*k4f + qB[5]*k5f + qB[6]*k6f + qB[7]*k7f;
    // Q carries -scale*log2e, so sigmoid = rcp(1 + exp2(dot))
    float sA = RCPF(1.f + EXP2F(dA));
    float sB = RCPF(1.f + EXP2F(dB));
    if (MASKED) {
      const int kk2 = k0 + j;
      sA = (kk2 <= rowA) ? sA : 0.f;              // exact: sigmoid(-1e9)==0
      sB = (kk2 <= rowB) ? sB : 0.f;
    }
    denA += sA; denB += sB;
    accA[0] += sA*va.x; accA[1] += sA*va.y; accA[2] += sA*va.z; accA[3] += sA*va.w;
    accA[4] += sA*vb.x; accA[5] += sA*vb.y; accA[6] += sA*vb.z; accA[7] += sA*vb.w;
    accB[0] += sB*va.x; accB[1] += sB*va.y; accB[2] += sB*va.z; accB[3] += sB*va.w;
    accB[4] += sB*vb.x; accB[5] += sB*vb.y; accB[6] += sB*vb.z; accB[7] += sB*vb.w;
  }
}

// ---------------------------------------------------------------------------
// Causal sigmoid-attention v4: bf16 Q/K (V fp32 exact).
// Block = (bh, m): 256 threads (4 waves), rows 128m..128m+127 of head bh.
// 4 waves split key-tiles round-robin; wave-private LDS double-buffered
// staging (48 B/key); partials combined through LDS. Heavy blocks first.
// ---------------------------------------------------------------------------
__global__ __launch_bounds__(256)
void attn_kernel(const unsigned* __restrict__ Qb, const unsigned* __restrict__ KVb,
                 float* __restrict__ out)
{
  __shared__ unsigned stage[4][2][64 * 12];       // 24 KB
  __shared__ float red[4][128][9];                // 18 KB

  const int bh   = blockIdx.x & 63;
  const int m    = 15 - (blockIdx.x >> 6);        // LPT: heavy first
  const int w    = threadIdx.x >> 6;
  const int lane = threadIdx.x & 63;
  const int rowA = m * 128 + lane;
  const int rowB = m * 128 + 64 + lane;
  const int ntiles = 2 * (m + 1);

  const uint4* gsrc = (const uint4*)(KVb + (size_t)bh * SEQ * 12);

  float qA[8], qB[8];
  {
    const uint4 a = *(const uint4*)(Qb + ((size_t)bh * SEQ + rowA) * 4);
    const uint4 b = *(const uint4*)(Qb + ((size_t)bh * SEQ + rowB) * 4);
    qA[0] = bflo(a.x); qA[1] = bfhi(a.x); qA[2] = bflo(a.y); qA[3] = bfhi(a.y);
    qA[4] = bflo(a.z); qA[5] = bfhi(a.z); qA[6] = bflo(a.w); qA[7] = bfhi(a.w);
    qB[0] = bflo(b.x); qB[1] = bfhi(b.x); qB[2] = bflo(b.y); qB[3] = bfhi(b.y);
    qB[4] = bflo(b.z); qB[5] = bfhi(b.z); qB[6] = bflo(b.w); qB[7] = bfhi(b.w);
  }

  float denA = 0.f, denB = 0.f;
  float accA[8], accB[8];
  #pragma unroll
  for (int i = 0; i < 8; ++i) { accA[i] = 0.f; accB[i] = 0.f; }

  unsigned* buf0 = &stage[w][0][0];
  unsigned* buf1 = &stage[w][1][0];

  uint4 ld0, ld1, ld2;                            // tile = 192 uint4
  if (w < ntiles) {                               // prologue: stage first tile
    ld0 = gsrc[w * 192 +   0 + lane];
    ld1 = gsrc[w * 192 +  64 + lane];
    ld2 = gsrc[w * 192 + 128 + lane];
    uint4* d = (uint4*)buf0;
    d[lane] = ld0; d[64 + lane] = ld1; d[128 + lane] = ld2;
  }

  int it = 0;
  for (int t = w; t < ntiles; t += 4, ++it) {
    unsigned* cur = (it & 1) ? buf1 : buf0;
    unsigned* nxt = (it & 1) ? buf0 : buf1;
    const int tn = t + 4;
    const bool pf = (tn < ntiles);
    if (pf) {                                     // prefetch next tile -> regs
      ld0 = gsrc[tn * 192 +   0 + lane];
      ld1 = gsrc[tn * 192 +  64 + lane];
      ld2 = gsrc[tn * 192 + 128 + lane];
    }
    const int k0 = t * 64;
    if (t >= 2 * m)
      attn_tile<true >(cur, k0, rowA, rowB, qA, qB, denA, denB, accA, accB);
    else
      attn_tile<false>(cur, k0, rowA, rowB, qA, qB, denA, denB, accA, accB);
    if (pf) {                                     // commit prefetched tile
      uint4* d = (uint4*)nxt;
      d[lane] = ld0; d[64 + lane] = ld1; d[128 + lane] = ld2;
    }
  }

  // write per-wave partials (stride 9 floats -> 2 lanes/bank, conflict-free)
  red[w][lane][0] = denA;
  #pragma unroll
  for (int i = 0; i < 8; ++i) red[w][lane][1 + i] = accA[i];
  red[w][64 + lane][0] = denB;
  #pragma unroll
  for (int i = 0; i < 8; ++i) red[w][64 + lane][1 + i] = accB[i];
  __syncthreads();

  if (w == 0) {
    float dA = 0.f, dB = 0.f, aA[8], aB[8];
    #pragma unroll
    for (int i = 0; i < 8; ++i) { aA[i] = 0.f; aB[i] = 0.f; }
    #pragma unroll
    for (int ww = 0; ww < 4; ++ww) {
      dA += red[ww][lane][0];
      dB += red[ww][64 + lane][0];
      #pragma unroll
      for (int i = 0; i < 8; ++i) {
        aA[i] += red[ww][lane][1 + i];
        aB[i] += red[ww][64 + lane][1 + i];
      }
    }
    const float iA = RCPF(dA);                    // den >= sigmoid(s_qq) > 0
    const float iB = RCPF(dB);
    const int b = bh >> 4, h = bh & 15;
    float* oA = out + ((size_t)(b * SEQ + rowA)) * EDIM + h * HDIM;
    float* oB = out + ((size_t)(b * SEQ + rowB)) * EDIM + h * HDIM;
    *(float4*)(oA)     = make_float4(aA[0]*iA, aA[1]*iA, aA[2]*iA, aA[3]*iA);
    *(float4*)(oA + 4) = make_float4(aA[4]*iA, aA[5]*iA, aA[6]*iA, aA[7]*iA);
    *(float4*)(oB)     = make_float4(aB[0]*iB, aB[1]*iB, aB[2]*iB, aB[3]*iB);
    *(float4*)(oB + 4) = make_float4(aB[4]*iB, aB[5]*iB, aB[6]*iB, aB[7]*iB);
  }
}

// ---------------------------------------------------------------------------
extern "C" void kernel_launch(void* const* d_in, const int* in_sizes, int n_in,
                              void* d_out, int out_size, void* d_ws, size_t ws_size,
                              hipStream_t stream)
{
  const float* x  = (const float*)d_in[0];
  const float* Wq = (const float*)d_in[1];
  const float* bq = (const float*)d_in[2];
  const float* Wk = (const float*)d_in[3];
  const float* bk = (const float*)d_in[4];
  const float* Wv = (const float*)d_in[5];
  const float* bv = (const float*)d_in[6];
  const float* Wo = (const float*)d_in[7];
  const float* bo = (const float*)d_in[8];

  float* ws = (float*)d_ws;
  // layout (floats): WT 65536 | attn 1048576 | Qb 524288 dw | KVb 1572864 dw
  float*    WT   = ws;
  float*    attn = ws + 65536;
  unsigned* Qb   = (unsigned*)(ws + 65536 + 1048576);
  unsigned* KVb  = Qb + (size_t)64 * SEQ * 4;

  transpose4_kernel<<<dim3(8, 4), 256, 0, stream>>>(Wq, Wk, Wv, Wo, WT);
  qkv_kernel<<<dim3(NROW / 32, 3), 256, 0, stream>>>(x, WT, bq, bk, bv, Qb, KVb);
  attn_kernel<<<dim3(64 * 16), 256, 0, stream>>>(Qb, KVb, attn);
  oproj_kernel<<<dim3(NROW / 32), 256, 0, stream>>>(attn, WT + 3 * EDIM * EDIM, bo,
                                                    (float*)d_out);
}